// Round 3
// baseline (958.973 us; speedup 1.0000x reference)
//
#include <hip/hip_runtime.h>

#define D_MODEL 768
#define BN 16
#define NROWS 32768
#define SCALE 0.1f
#define LN_EPS 1e-5f
#define TPB 1024
#define WAVES 16
#define RPW 4                                 // rows per wave per pass
#define PASSES 2
#define ROWS_PER_BLOCK (WAVES * RPW * PASSES) // 128
#define NBLOCKS (NROWS / ROWS_PER_BLOCK)      // 256  -> exactly 1 block/CU

__device__ __forceinline__ void ld4(const float* p, float* d) {
    float4 v = *(const float4*)p;
    d[0] = v.x; d[1] = v.y; d[2] = v.z; d[3] = v.w;
}
// wave-uniform broadcast from a compile-time lane: v_readlane -> SGPR operand
__device__ __forceinline__ float bcast(float v, int l) {
    return __int_as_float(__builtin_amdgcn_readlane(__float_as_int(v), l));
}

__global__ __launch_bounds__(TPB)
void adapter_fused(const float* __restrict__ x,
                   const float* __restrict__ gamma,
                   const float* __restrict__ beta,
                   const float* __restrict__ w_down,
                   const float* __restrict__ b_down,
                   const float* __restrict__ w_up,
                   const float* __restrict__ b_up,
                   float* __restrict__ out)
{
    // LN folded into weights:  down_pre[k] = rs*(P[k] - mean*G[k]) + D[k]
    //   P[k] = sum_d x_d * (g_d * wd[d][k])   (s_wd holds g-prescaled wd^T)
    //   G[k] = sum_d g_d * wd[d][k],  D[k] = sum_d beta_d * wd[d][k]
    __shared__ __align__(16) float s_wd[BN * D_MODEL];  // 48 KB, [k][d], g-scaled
    __shared__ __align__(16) float s_wu[BN * D_MODEL];  // 48 KB, [k][d], SCALE-scaled
    __shared__ __align__(16) float s_bu[D_MODEL];       // SCALE * b_up
    __shared__ float s_g [D_MODEL];
    __shared__ float s_bt[D_MODEL];
    __shared__ float s_bd[BN];
    __shared__ float s_G [BN];
    __shared__ float s_D [BN];

    const int t    = threadIdx.x;
    const int w    = t >> 6;
    const int lane = t & 63;

    // ---------------- staging, once per block ----------------
    if (t < D_MODEL) {
        const float4* wr = (const float4*)(w_down + (size_t)t * BN);
        #pragma unroll
        for (int q = 0; q < 4; ++q) {
            float4 v = wr[q];
            s_wd[(q*4+0)*D_MODEL + t] = v.x;
            s_wd[(q*4+1)*D_MODEL + t] = v.y;
            s_wd[(q*4+2)*D_MODEL + t] = v.z;
            s_wd[(q*4+3)*D_MODEL + t] = v.w;
        }
        s_g [t] = gamma[t];
        s_bt[t] = beta[t];
        s_bu[t] = SCALE * b_up[t];
    }
    {   // w_up (16,768) straight copy, pre-scaled by SCALE
        const float4* src = (const float4*)w_up;
        float4* dst = (float4*)s_wu;
        #pragma unroll
        for (int q = 0; q < 3; ++q) {
            float4 v = src[t + q * TPB];
            v.x *= SCALE; v.y *= SCALE; v.z *= SCALE; v.w *= SCALE;
            dst[t + q * TPB] = v;
        }
    }
    if (t < BN) s_bd[t] = b_down[t];
    __syncthreads();

    // wave k (=w): compute G[k], D[k]; then scale s_wd row k by gamma
    {
        const int k = w;
        float Gp = 0.f, Dp = 0.f;
        #pragma unroll
        for (int q = 0; q < 3; ++q) {
            const int d0 = q * 256 + lane * 4;
            float wv[4], gv[4], bv[4];
            ld4(&s_wd[k * D_MODEL + d0], wv);
            ld4(&s_g [d0], gv);
            ld4(&s_bt[d0], bv);
            #pragma unroll
            for (int c = 0; c < 4; ++c) {
                Gp = fmaf(gv[c], wv[c], Gp);
                Dp = fmaf(bv[c], wv[c], Dp);
                wv[c] *= gv[c];
            }
            *(float4*)&s_wd[k * D_MODEL + d0] = make_float4(wv[0], wv[1], wv[2], wv[3]);
        }
        #pragma unroll
        for (int m = 32; m >= 1; m >>= 1) {
            Gp += __shfl_xor(Gp, m, 64);
            Dp += __shfl_xor(Dp, m, 64);
        }
        if (lane == 0) { s_G[k] = Gp; s_D[k] = Dp; }
    }
    __syncthreads();            // last block-wide barrier

    // block-invariant per-lane constants (k split: A = lane&7, B = 8+(lane&7))
    const int   kA  = lane & 7;
    const float GlA = s_G[kA],          GlB = s_G[8 + kA];
    const float DBA = s_D[kA] + s_bd[kA];
    const float DBB = s_D[8 + kA] + s_bd[8 + kA];
    const float inv_d = 1.0f / (float)D_MODEL;
    const int   dofs = lane * 4;        // chunked d-ownership: d = q*256 + lane*4

    for (int pp = 0; pp < PASSES; ++pp) {
        const int r0 = blockIdx.x * ROWS_PER_BLOCK + pp * (WAVES * RPW) + w * RPW;
        const float* xp = x + (size_t)r0 * D_MODEL;

        // ---- load 4 rows; each instr is contiguous 1KB/wave ----
        float xv[RPW][12];
        #pragma unroll
        for (int j = 0; j < RPW; ++j)
            #pragma unroll
            for (int q = 0; q < 3; ++q)
                ld4(xp + (size_t)j * D_MODEL + q * 256 + dofs, &xv[j][q * 4]);

        // ---- LN stats, 4 independent in-wave butterflies ----
        float s1[RPW], s2[RPW];
        #pragma unroll
        for (int j = 0; j < RPW; ++j) {
            s1[j] = 0.f; s2[j] = 0.f;
            #pragma unroll
            for (int i = 0; i < 12; ++i) {
                s1[j] += xv[j][i];
                s2[j]  = fmaf(xv[j][i], xv[j][i], s2[j]);
            }
        }
        #pragma unroll
        for (int m = 32; m >= 1; m >>= 1) {
            #pragma unroll
            for (int j = 0; j < RPW; ++j) {
                s1[j] += __shfl_xor(s1[j], m, 64);
                s2[j] += __shfl_xor(s2[j], m, 64);
            }
        }
        float mean[RPW], rs[RPW];
        #pragma unroll
        for (int j = 0; j < RPW; ++j) {
            mean[j] = s1[j] * inv_d;
            rs[j]   = rsqrtf(fmaf(s2[j], inv_d, -(mean[j] * mean[j])) + LN_EPS);
        }

        // ---- down-proj on RAW x (LN folded), two 8-k batches ----
        float dnA[RPW], dnB[RPW];
        #pragma unroll
        for (int h = 0; h < 2; ++h) {          // h=0: k 0..7, h=1: k 8..15
            float p[RPW][8];
            #pragma unroll
            for (int j = 0; j < RPW; ++j)
                #pragma unroll
                for (int i = 0; i < 8; ++i) p[j][i] = 0.f;
            #pragma unroll
            for (int kk = 0; kk < 8; ++kk) {
                const int k = h * 8 + kk;
                #pragma unroll
                for (int q = 0; q < 3; ++q) {
                    float wv[4];
                    ld4(&s_wd[k * D_MODEL + q * 256 + dofs], wv);
                    #pragma unroll
                    for (int j = 0; j < RPW; ++j)
                        #pragma unroll
                        for (int c = 0; c < 4; ++c)
                            p[j][kk] = fmaf(xv[j][q * 4 + c], wv[c], p[j][kk]);
                }
            }
            // split-butterfly: 8 elems over 8-lane groups, then fold groups
            #pragma unroll
            for (int m = 4; m >= 1; m >>= 1) {
                const bool up = (lane & m) != 0;
                #pragma unroll
                for (int j = 0; j < RPW; ++j)
                    #pragma unroll
                    for (int i = 0; i < m; ++i) {
                        float s = up ? p[j][i] : p[j][i + m];
                        float r = __shfl_xor(s, m, 64);
                        p[j][i] = (up ? p[j][i + m] : p[j][i]) + r;
                    }
            }
            #pragma unroll
            for (int j = 0; j < RPW; ++j) {
                float v = p[j][0];
                v += __shfl_xor(v, 8, 64);
                v += __shfl_xor(v, 16, 64);
                v += __shfl_xor(v, 32, 64);
                // lane now holds P[k] for k = h*8 + (lane&7), summed over wave
                const float G = h ? GlB : GlA;
                const float DB = h ? DBB : DBA;
                const float dv = fmaxf(fmaf(rs[j], fmaf(-mean[j], G, v), DB), 0.f);
                if (h) dnB[j] = dv; else dnA[j] = dv;
            }
        }

        // ---- up-proj: dn via v_readlane (SGPR operand), weights from LDS ----
        float a[RPW][12];
        {
            float buv[12];
            #pragma unroll
            for (int q = 0; q < 3; ++q) ld4(&s_bu[q * 256 + dofs], &buv[q * 4]);
            #pragma unroll
            for (int j = 0; j < RPW; ++j)
                #pragma unroll
                for (int i = 0; i < 12; ++i) a[j][i] = buv[i];
        }
        #pragma unroll
        for (int k = 0; k < BN; ++k) {
            float db[RPW];
            #pragma unroll
            for (int j = 0; j < RPW; ++j)
                db[j] = (k < 8) ? bcast(dnA[j], k) : bcast(dnB[j], k - 8);
            #pragma unroll
            for (int q = 0; q < 3; ++q) {
                float wv[4];
                ld4(&s_wu[k * D_MODEL + q * 256 + dofs], wv);
                #pragma unroll
                for (int j = 0; j < RPW; ++j)
                    #pragma unroll
                    for (int c = 0; c < 4; ++c)
                        a[j][q * 4 + c] = fmaf(db[j], wv[c], a[j][q * 4 + c]);
            }
        }

        // ---- residual (x still in regs) + store, contiguous 1KB/instr ----
        float* op = out + (size_t)r0 * D_MODEL;
        #pragma unroll
        for (int j = 0; j < RPW; ++j) {
            #pragma unroll
            for (int q = 0; q < 3; ++q) {
                float4 o;
                o.x = xv[j][q*4+0] + a[j][q*4+0];
                o.y = xv[j][q*4+1] + a[j][q*4+1];
                o.z = xv[j][q*4+2] + a[j][q*4+2];
                o.w = xv[j][q*4+3] + a[j][q*4+3];
                *(float4*)(op + (size_t)j * D_MODEL + q * 256 + dofs) = o;
            }
        }
    }
}

extern "C" void kernel_launch(void* const* d_in, const int* in_sizes, int n_in,
                              void* d_out, int out_size, void* d_ws, size_t ws_size,
                              hipStream_t stream) {
    const float* x       = (const float*)d_in[0];
    const float* gamma   = (const float*)d_in[1];
    const float* beta    = (const float*)d_in[2];
    const float* w_down  = (const float*)d_in[3];
    const float* b_down  = (const float*)d_in[4];
    const float* w_up    = (const float*)d_in[5];
    const float* b_up    = (const float*)d_in[6];
    float* out = (float*)d_out;

    adapter_fused<<<NBLOCKS, TPB, 0, stream>>>(x, gamma, beta, w_down, b_down,
                                               w_up, b_up, out);
}

// Round 4
// 794.459 us; speedup vs baseline: 1.2071x; 1.2071x over previous
//
#include <hip/hip_runtime.h>

#define D_MODEL 768
#define BN 16
#define NROWS 32768
#define SCALE 0.1f
#define LN_EPS 1e-5f
#define TPB 1024
#define WAVES 16
#define RPW 4                                 // rows per wave per pass
#define PASSES 2
#define ROWS_PER_BLOCK (WAVES * RPW * PASSES) // 128
#define NBLOCKS (NROWS / ROWS_PER_BLOCK)      // 256  -> exactly 1 block/CU

__device__ __forceinline__ void ld4(const float* p, float* d) {
    float4 v = *(const float4*)p;
    d[0] = v.x; d[1] = v.y; d[2] = v.z; d[3] = v.w;
}
// wave-uniform broadcast from a compile-time lane: v_readlane -> SGPR operand
__device__ __forceinline__ float bcast(float v, int l) {
    return __int_as_float(__builtin_amdgcn_readlane(__float_as_int(v), l));
}

// 4 waves/EU minimum => 16 waves/CU co-resident (our 1024-thread block),
// and -- critically -- a 128-VGPR budget instead of the default 64.
// R3 post-mortem: without this the allocator targeted 64 VGPRs and spilled
// ~1.4 GB of scratch traffic to HBM (FETCH 1.55 GB, dur 845 us).
__global__ __launch_bounds__(TPB, 4)
void adapter_fused(const float* __restrict__ x,
                   const float* __restrict__ gamma,
                   const float* __restrict__ beta,
                   const float* __restrict__ w_down,
                   const float* __restrict__ b_down,
                   const float* __restrict__ w_up,
                   const float* __restrict__ b_up,
                   float* __restrict__ out)
{
    // LN folded into weights:  down_pre[k] = rs*(P[k] - mean*G[k]) + D[k] + bd[k]
    //   P[k] = sum_d x_d * (g_d * wd[d][k])   (s_wd holds g-prescaled wd^T)
    //   G[k] = sum_d g_d * wd[d][k],  D[k] = sum_d beta_d * wd[d][k]
    __shared__ __align__(16) float s_wd[BN * D_MODEL];  // 48 KB, [k][d], g-scaled
    __shared__ __align__(16) float s_wu[BN * D_MODEL];  // 48 KB, [k][d], SCALE-scaled
    __shared__ __align__(16) float s_bu[D_MODEL];       // SCALE * b_up
    __shared__ float s_g [D_MODEL];
    __shared__ float s_bt[D_MODEL];
    __shared__ float s_bd[BN];
    __shared__ float s_G [BN];
    __shared__ float s_D [BN];

    const int t    = threadIdx.x;
    const int w    = t >> 6;
    const int lane = t & 63;

    // ---------------- staging, once per block ----------------
    if (t < D_MODEL) {
        const float4* wr = (const float4*)(w_down + (size_t)t * BN);
        #pragma unroll
        for (int q = 0; q < 4; ++q) {
            float4 v = wr[q];
            s_wd[(q*4+0)*D_MODEL + t] = v.x;
            s_wd[(q*4+1)*D_MODEL + t] = v.y;
            s_wd[(q*4+2)*D_MODEL + t] = v.z;
            s_wd[(q*4+3)*D_MODEL + t] = v.w;
        }
        s_g [t] = gamma[t];
        s_bt[t] = beta[t];
        s_bu[t] = SCALE * b_up[t];
    }
    {   // w_up (16,768) straight copy, pre-scaled by SCALE
        const float4* src = (const float4*)w_up;
        float4* dst = (float4*)s_wu;
        #pragma unroll
        for (int q = 0; q < 3; ++q) {
            float4 v = src[t + q * TPB];
            v.x *= SCALE; v.y *= SCALE; v.z *= SCALE; v.w *= SCALE;
            dst[t + q * TPB] = v;
        }
    }
    if (t < BN) s_bd[t] = b_down[t];
    __syncthreads();

    // wave k (=w): compute G[k], D[k]; then scale s_wd row k by gamma
    {
        const int k = w;
        float Gp = 0.f, Dp = 0.f;
        #pragma unroll
        for (int q = 0; q < 3; ++q) {
            const int d0 = q * 256 + lane * 4;
            float wv[4], gv[4], bv[4];
            ld4(&s_wd[k * D_MODEL + d0], wv);
            ld4(&s_g [d0], gv);
            ld4(&s_bt[d0], bv);
            #pragma unroll
            for (int c = 0; c < 4; ++c) {
                Gp = fmaf(gv[c], wv[c], Gp);
                Dp = fmaf(bv[c], wv[c], Dp);
                wv[c] *= gv[c];
            }
            *(float4*)&s_wd[k * D_MODEL + d0] = make_float4(wv[0], wv[1], wv[2], wv[3]);
        }
        #pragma unroll
        for (int m = 32; m >= 1; m >>= 1) {
            Gp += __shfl_xor(Gp, m, 64);
            Dp += __shfl_xor(Dp, m, 64);
        }
        if (lane == 0) { s_G[k] = Gp; s_D[k] = Dp; }
    }
    __syncthreads();            // last block-wide barrier

    // block-invariant per-lane constants (k split: A = lane&7, B = 8+(lane&7))
    const int   kA  = lane & 7;
    const float GlA = s_G[kA],          GlB = s_G[8 + kA];
    const float DBA = s_D[kA] + s_bd[kA];
    const float DBB = s_D[8 + kA] + s_bd[8 + kA];
    const float inv_d = 1.0f / (float)D_MODEL;
    const int   dofs = lane * 4;        // chunked d-ownership: d = q*256 + lane*4

    for (int pp = 0; pp < PASSES; ++pp) {
        const int r0 = blockIdx.x * ROWS_PER_BLOCK + pp * (WAVES * RPW) + w * RPW;
        const float* xp = x + (size_t)r0 * D_MODEL;

        // ---- load 4 rows; each instr is contiguous 1KB/wave ----
        float xv[RPW][12];
        #pragma unroll
        for (int j = 0; j < RPW; ++j)
            #pragma unroll
            for (int q = 0; q < 3; ++q)
                ld4(xp + (size_t)j * D_MODEL + q * 256 + dofs, &xv[j][q * 4]);

        // ---- LN stats, 4 independent in-wave butterflies ----
        float s1[RPW], s2[RPW];
        #pragma unroll
        for (int j = 0; j < RPW; ++j) {
            s1[j] = 0.f; s2[j] = 0.f;
            #pragma unroll
            for (int i = 0; i < 12; ++i) {
                s1[j] += xv[j][i];
                s2[j]  = fmaf(xv[j][i], xv[j][i], s2[j]);
            }
        }
        #pragma unroll
        for (int m = 32; m >= 1; m >>= 1) {
            #pragma unroll
            for (int j = 0; j < RPW; ++j) {
                s1[j] += __shfl_xor(s1[j], m, 64);
                s2[j] += __shfl_xor(s2[j], m, 64);
            }
        }
        float mean[RPW], rs[RPW];
        #pragma unroll
        for (int j = 0; j < RPW; ++j) {
            mean[j] = s1[j] * inv_d;
            rs[j]   = rsqrtf(fmaf(s2[j], inv_d, -(mean[j] * mean[j])) + LN_EPS);
        }

        // ---- down-proj on RAW x (LN folded), two 8-k batches ----
        float dnA[RPW], dnB[RPW];
        #pragma unroll
        for (int h = 0; h < 2; ++h) {          // h=0: k 0..7, h=1: k 8..15
            float p[RPW][8];
            #pragma unroll
            for (int j = 0; j < RPW; ++j)
                #pragma unroll
                for (int i = 0; i < 8; ++i) p[j][i] = 0.f;
            #pragma unroll
            for (int kk = 0; kk < 8; ++kk) {
                const int k = h * 8 + kk;
                #pragma unroll
                for (int q = 0; q < 3; ++q) {
                    float wv[4];
                    ld4(&s_wd[k * D_MODEL + q * 256 + dofs], wv);
                    #pragma unroll
                    for (int j = 0; j < RPW; ++j)
                        #pragma unroll
                        for (int c = 0; c < 4; ++c)
                            p[j][kk] = fmaf(xv[j][q * 4 + c], wv[c], p[j][kk]);
                }
            }
            // split-butterfly: 8 elems over 8-lane groups, then fold groups
            #pragma unroll
            for (int m = 4; m >= 1; m >>= 1) {
                const bool up = (lane & m) != 0;
                #pragma unroll
                for (int j = 0; j < RPW; ++j)
                    #pragma unroll
                    for (int i = 0; i < m; ++i) {
                        float s = up ? p[j][i] : p[j][i + m];
                        float r = __shfl_xor(s, m, 64);
                        p[j][i] = (up ? p[j][i + m] : p[j][i]) + r;
                    }
            }
            #pragma unroll
            for (int j = 0; j < RPW; ++j) {
                float v = p[j][0];
                v += __shfl_xor(v, 8, 64);
                v += __shfl_xor(v, 16, 64);
                v += __shfl_xor(v, 32, 64);
                // lane now holds P[k] for k = h*8 + (lane&7), summed over wave
                const float G  = h ? GlB : GlA;
                const float DB = h ? DBB : DBA;
                const float dv = fmaxf(fmaf(rs[j], fmaf(-mean[j], G, v), DB), 0.f);
                if (h) dnB[j] = dv; else dnA[j] = dv;
            }
        }

        // ---- up-proj + residual + store, per 256-d chunk (caps reg pressure:
        // acc[4][4] live instead of a[4][12]; dn broadcast via v_readlane ->
        // SGPR operand, ~zero VGPR cost) ----
        float* op = out + (size_t)r0 * D_MODEL;
        #pragma unroll
        for (int q = 0; q < 3; ++q) {
            float buv[4];
            ld4(&s_bu[q * 256 + dofs], buv);
            float acc[RPW][4];
            #pragma unroll
            for (int j = 0; j < RPW; ++j)
                #pragma unroll
                for (int c = 0; c < 4; ++c) acc[j][c] = buv[c];

            #pragma unroll
            for (int k = 0; k < BN; ++k) {
                float wv[4];
                ld4(&s_wu[k * D_MODEL + q * 256 + dofs], wv);
                float dbk[RPW];
                #pragma unroll
                for (int j = 0; j < RPW; ++j)
                    dbk[j] = (k < 8) ? bcast(dnA[j], k) : bcast(dnB[j], k - 8);
                #pragma unroll
                for (int j = 0; j < RPW; ++j)
                    #pragma unroll
                    for (int c = 0; c < 4; ++c)
                        acc[j][c] = fmaf(dbk[j], wv[c], acc[j][c]);
            }
            #pragma unroll
            for (int j = 0; j < RPW; ++j) {
                float4 o;
                o.x = xv[j][q*4+0] + acc[j][0];
                o.y = xv[j][q*4+1] + acc[j][1];
                o.z = xv[j][q*4+2] + acc[j][2];
                o.w = xv[j][q*4+3] + acc[j][3];
                *(float4*)(op + (size_t)j * D_MODEL + q * 256 + dofs) = o;
            }
        }
    }
}

extern "C" void kernel_launch(void* const* d_in, const int* in_sizes, int n_in,
                              void* d_out, int out_size, void* d_ws, size_t ws_size,
                              hipStream_t stream) {
    const float* x       = (const float*)d_in[0];
    const float* gamma   = (const float*)d_in[1];
    const float* beta    = (const float*)d_in[2];
    const float* w_down  = (const float*)d_in[3];
    const float* b_down  = (const float*)d_in[4];
    const float* w_up    = (const float*)d_in[5];
    const float* b_up    = (const float*)d_in[6];
    float* out = (float*)d_out;

    adapter_fused<<<NBLOCKS, TPB, 0, stream>>>(x, gamma, beta, w_down, b_down,
                                               w_up, b_up, out);
}

// Round 5
// 792.941 us; speedup vs baseline: 1.2094x; 1.0019x over previous
//
#include <hip/hip_runtime.h>

#define D_MODEL 768
#define BN 16
#define NROWS 32768
#define SCALE 0.1f
#define LN_EPS 1e-5f
#define TPB 1024
#define WAVES 16
#define RPW 4                                 // rows per wave per pass
#define PASSES 2
#define ROWS_PER_BLOCK (WAVES * RPW * PASSES) // 128
#define NBLOCKS (NROWS / ROWS_PER_BLOCK)      // 256  -> exactly 1 block/CU

__device__ __forceinline__ void ld4(const float* p, float* d) {
    float4 v = *(const float4*)p;
    d[0] = v.x; d[1] = v.y; d[2] = v.z; d[3] = v.w;
}
// wave-uniform broadcast from a compile-time lane: v_readlane -> SGPR operand
__device__ __forceinline__ float bcast(float v, int l) {
    return __int_as_float(__builtin_amdgcn_readlane(__float_as_int(v), l));
}

// R4 post-mortem: __launch_bounds__(1024, 4) did NOT raise the VGPR budget
// (VGPR_Count stayed 64, FETCH 1.29 GB of spill traffic). Pin the budget
// directly: waves_per_eu(4,4) => exactly 4 waves/SIMD => 512/4 = 128 VGPRs.
// LDS (108 KB) already restricts us to 1 block/CU = 16 waves = 4 waves/EU,
// so this attribute costs zero occupancy -- it only widens the register file.
__global__ __launch_bounds__(TPB)
__attribute__((amdgpu_waves_per_eu(4, 4)))
void adapter_fused(const float* __restrict__ x,
                   const float* __restrict__ gamma,
                   const float* __restrict__ beta,
                   const float* __restrict__ w_down,
                   const float* __restrict__ b_down,
                   const float* __restrict__ w_up,
                   const float* __restrict__ b_up,
                   float* __restrict__ out)
{
    // LN folded into weights:  down_pre[k] = rs*(P[k] - mean*G[k]) + D[k] + bd[k]
    //   P[k] = sum_d x_d * (g_d * wd[d][k])   (s_wd holds g-prescaled wd^T)
    //   G[k] = sum_d g_d * wd[d][k],  D[k] = sum_d beta_d * wd[d][k]
    __shared__ __align__(16) float s_wd[BN * D_MODEL];  // 48 KB, [k][d], g-scaled
    __shared__ __align__(16) float s_wu[BN * D_MODEL];  // 48 KB, [k][d], SCALE-scaled
    __shared__ __align__(16) float s_bu[D_MODEL];       // SCALE * b_up
    __shared__ float s_g [D_MODEL];
    __shared__ float s_bt[D_MODEL];
    __shared__ float s_bd[BN];
    __shared__ float s_G [BN];
    __shared__ float s_D [BN];

    const int t    = threadIdx.x;
    const int w    = t >> 6;
    const int lane = t & 63;

    // ---------------- staging, once per block ----------------
    if (t < D_MODEL) {
        const float4* wr = (const float4*)(w_down + (size_t)t * BN);
        #pragma unroll
        for (int q = 0; q < 4; ++q) {
            float4 v = wr[q];
            s_wd[(q*4+0)*D_MODEL + t] = v.x;
            s_wd[(q*4+1)*D_MODEL + t] = v.y;
            s_wd[(q*4+2)*D_MODEL + t] = v.z;
            s_wd[(q*4+3)*D_MODEL + t] = v.w;
        }
        s_g [t] = gamma[t];
        s_bt[t] = beta[t];
        s_bu[t] = SCALE * b_up[t];
    }
    {   // w_up (16,768) straight copy, pre-scaled by SCALE
        const float4* src = (const float4*)w_up;
        float4* dst = (float4*)s_wu;
        #pragma unroll
        for (int q = 0; q < 3; ++q) {
            float4 v = src[t + q * TPB];
            v.x *= SCALE; v.y *= SCALE; v.z *= SCALE; v.w *= SCALE;
            dst[t + q * TPB] = v;
        }
    }
    if (t < BN) s_bd[t] = b_down[t];
    __syncthreads();

    // wave k (=w): compute G[k], D[k]; then scale s_wd row k by gamma
    {
        const int k = w;
        float Gp = 0.f, Dp = 0.f;
        #pragma unroll
        for (int q = 0; q < 3; ++q) {
            const int d0 = q * 256 + lane * 4;
            float wv[4], gv[4], bv[4];
            ld4(&s_wd[k * D_MODEL + d0], wv);
            ld4(&s_g [d0], gv);
            ld4(&s_bt[d0], bv);
            #pragma unroll
            for (int c = 0; c < 4; ++c) {
                Gp = fmaf(gv[c], wv[c], Gp);
                Dp = fmaf(bv[c], wv[c], Dp);
                wv[c] *= gv[c];
            }
            *(float4*)&s_wd[k * D_MODEL + d0] = make_float4(wv[0], wv[1], wv[2], wv[3]);
        }
        #pragma unroll
        for (int m = 32; m >= 1; m >>= 1) {
            Gp += __shfl_xor(Gp, m, 64);
            Dp += __shfl_xor(Dp, m, 64);
        }
        if (lane == 0) { s_G[k] = Gp; s_D[k] = Dp; }
    }
    __syncthreads();            // last block-wide barrier

    // block-invariant per-lane constants (k split: A = lane&7, B = 8+(lane&7))
    const int   kA  = lane & 7;
    const float GlA = s_G[kA],          GlB = s_G[8 + kA];
    const float DBA = s_D[kA] + s_bd[kA];
    const float DBB = s_D[8 + kA] + s_bd[8 + kA];
    const float inv_d = 1.0f / (float)D_MODEL;
    const int   dofs = lane * 4;        // chunked d-ownership: d = q*256 + lane*4

    for (int pp = 0; pp < PASSES; ++pp) {
        const int r0 = blockIdx.x * ROWS_PER_BLOCK + pp * (WAVES * RPW) + w * RPW;
        const float* xp = x + (size_t)r0 * D_MODEL;

        // ---- load 4 rows; each instr is contiguous 1KB/wave ----
        float xv[RPW][12];
        #pragma unroll
        for (int j = 0; j < RPW; ++j)
            #pragma unroll
            for (int q = 0; q < 3; ++q)
                ld4(xp + (size_t)j * D_MODEL + q * 256 + dofs, &xv[j][q * 4]);

        // ---- LN stats, 4 independent in-wave butterflies ----
        float s1[RPW], s2[RPW];
        #pragma unroll
        for (int j = 0; j < RPW; ++j) {
            s1[j] = 0.f; s2[j] = 0.f;
            #pragma unroll
            for (int i = 0; i < 12; ++i) {
                s1[j] += xv[j][i];
                s2[j]  = fmaf(xv[j][i], xv[j][i], s2[j]);
            }
        }
        #pragma unroll
        for (int m = 32; m >= 1; m >>= 1) {
            #pragma unroll
            for (int j = 0; j < RPW; ++j) {
                s1[j] += __shfl_xor(s1[j], m, 64);
                s2[j] += __shfl_xor(s2[j], m, 64);
            }
        }
        float mean[RPW], rs[RPW];
        #pragma unroll
        for (int j = 0; j < RPW; ++j) {
            mean[j] = s1[j] * inv_d;
            rs[j]   = rsqrtf(fmaf(s2[j], inv_d, -(mean[j] * mean[j])) + LN_EPS);
        }

        // ---- down-proj on RAW x (LN folded), two 8-k batches ----
        float dnA[RPW], dnB[RPW];
        #pragma unroll
        for (int h = 0; h < 2; ++h) {          // h=0: k 0..7, h=1: k 8..15
            float p[RPW][8];
            #pragma unroll
            for (int j = 0; j < RPW; ++j)
                #pragma unroll
                for (int i = 0; i < 8; ++i) p[j][i] = 0.f;
            #pragma unroll
            for (int kk = 0; kk < 8; ++kk) {
                const int k = h * 8 + kk;
                #pragma unroll
                for (int q = 0; q < 3; ++q) {
                    float wv[4];
                    ld4(&s_wd[k * D_MODEL + q * 256 + dofs], wv);
                    #pragma unroll
                    for (int j = 0; j < RPW; ++j)
                        #pragma unroll
                        for (int c = 0; c < 4; ++c)
                            p[j][kk] = fmaf(xv[j][q * 4 + c], wv[c], p[j][kk]);
                }
            }
            // split-butterfly: 8 elems over 8-lane groups, then fold groups
            #pragma unroll
            for (int m = 4; m >= 1; m >>= 1) {
                const bool up = (lane & m) != 0;
                #pragma unroll
                for (int j = 0; j < RPW; ++j)
                    #pragma unroll
                    for (int i = 0; i < m; ++i) {
                        float s = up ? p[j][i] : p[j][i + m];
                        float r = __shfl_xor(s, m, 64);
                        p[j][i] = (up ? p[j][i + m] : p[j][i]) + r;
                    }
            }
            #pragma unroll
            for (int j = 0; j < RPW; ++j) {
                float v = p[j][0];
                v += __shfl_xor(v, 8, 64);
                v += __shfl_xor(v, 16, 64);
                v += __shfl_xor(v, 32, 64);
                // lane now holds P[k] for k = h*8 + (lane&7), summed over wave
                const float G  = h ? GlB : GlA;
                const float DB = h ? DBB : DBA;
                const float dv = fmaxf(fmaf(rs[j], fmaf(-mean[j], G, v), DB), 0.f);
                if (h) dnB[j] = dv; else dnA[j] = dv;
            }
        }

        // ---- up-proj + residual + store, per 256-d chunk (caps reg pressure:
        // acc[4][4] live instead of a[4][12]; dn broadcast via v_readlane ->
        // SGPR operand, ~zero VGPR cost) ----
        float* op = out + (size_t)r0 * D_MODEL;
        #pragma unroll
        for (int q = 0; q < 3; ++q) {
            float buv[4];
            ld4(&s_bu[q * 256 + dofs], buv);
            float acc[RPW][4];
            #pragma unroll
            for (int j = 0; j < RPW; ++j)
                #pragma unroll
                for (int c = 0; c < 4; ++c) acc[j][c] = buv[c];

            #pragma unroll
            for (int k = 0; k < BN; ++k) {
                float wv[4];
                ld4(&s_wu[k * D_MODEL + q * 256 + dofs], wv);
                float dbk[RPW];
                #pragma unroll
                for (int j = 0; j < RPW; ++j)
                    dbk[j] = (k < 8) ? bcast(dnA[j], k) : bcast(dnB[j], k - 8);
                #pragma unroll
                for (int j = 0; j < RPW; ++j)
                    #pragma unroll
                    for (int c = 0; c < 4; ++c)
                        acc[j][c] = fmaf(dbk[j], wv[c], acc[j][c]);
            }
            #pragma unroll
            for (int j = 0; j < RPW; ++j) {
                float4 o;
                o.x = xv[j][q*4+0] + acc[j][0];
                o.y = xv[j][q*4+1] + acc[j][1];
                o.z = xv[j][q*4+2] + acc[j][2];
                o.w = xv[j][q*4+3] + acc[j][3];
                *(float4*)(op + (size_t)j * D_MODEL + q * 256 + dofs) = o;
            }
        }
    }
}

extern "C" void kernel_launch(void* const* d_in, const int* in_sizes, int n_in,
                              void* d_out, int out_size, void* d_ws, size_t ws_size,
                              hipStream_t stream) {
    const float* x       = (const float*)d_in[0];
    const float* gamma   = (const float*)d_in[1];
    const float* beta    = (const float*)d_in[2];
    const float* w_down  = (const float*)d_in[3];
    const float* b_down  = (const float*)d_in[4];
    const float* w_up    = (const float*)d_in[5];
    const float* b_up    = (const float*)d_in[6];
    float* out = (float*)d_out;

    adapter_fused<<<NBLOCKS, TPB, 0, stream>>>(x, gamma, beta, w_down, b_down,
                                               w_up, b_up, out);
}

// Round 6
// 762.396 us; speedup vs baseline: 1.2578x; 1.0401x over previous
//
#include <hip/hip_runtime.h>

#define D_MODEL 768
#define BN 16
#define NROWS 32768
#define SCALE 0.1f
#define LN_EPS 1e-5f
#define TPB 1024
#define WAVES 16
#define RPW 2                                 // rows per wave per pass (fits 64 VGPRs)
#define PASSES 4
#define ROWS_PER_BLOCK (WAVES * RPW * PASSES) // 128
#define NBLOCKS (NROWS / ROWS_PER_BLOCK)      // 256  -> exactly 1 block/CU

__device__ __forceinline__ void ld4(const float* p, float* d) {
    float4 v = *(const float4*)p;
    d[0] = v.x; d[1] = v.y; d[2] = v.z; d[3] = v.w;
}
// wave-uniform broadcast from a compile-time lane: v_readlane -> SGPR operand
__device__ __forceinline__ float bcast(float v, int l) {
    return __int_as_float(__builtin_amdgcn_readlane(__float_as_int(v), l));
}

// R5 post-mortem: at TPB=1024 the toolchain pins the VGPR budget at 64 and
// ignores both __launch_bounds__(,N) and amdgpu_waves_per_eu. So the kernel
// must FIT 64 VGPRs: RPW=2 (live set ~52) instead of RPW=4 (~120, spilled
// 1.3 GB of scratch traffic). Structure otherwise identical to R4.
__global__ __launch_bounds__(TPB)
void adapter_fused(const float* __restrict__ x,
                   const float* __restrict__ gamma,
                   const float* __restrict__ beta,
                   const float* __restrict__ w_down,
                   const float* __restrict__ b_down,
                   const float* __restrict__ w_up,
                   const float* __restrict__ b_up,
                   float* __restrict__ out)
{
    // LN folded into weights:  down_pre[k] = rs*(P[k] - mean*G[k]) + D[k] + bd[k]
    //   P[k] = sum_d x_d * (g_d * wd[d][k])   (s_wd holds g-prescaled wd^T)
    //   G[k] = sum_d g_d * wd[d][k],  D[k] = sum_d beta_d * wd[d][k]
    __shared__ __align__(16) float s_wd[BN * D_MODEL];  // 48 KB, [k][d], g-scaled
    __shared__ __align__(16) float s_wu[BN * D_MODEL];  // 48 KB, [k][d], SCALE-scaled
    __shared__ __align__(16) float s_bu[D_MODEL];       // SCALE * b_up
    __shared__ float s_g [D_MODEL];
    __shared__ float s_bt[D_MODEL];
    __shared__ float s_bd[BN];
    __shared__ float s_G [BN];
    __shared__ float s_D [BN];

    const int t    = threadIdx.x;
    const int w    = t >> 6;
    const int lane = t & 63;

    // ---------------- staging, once per block ----------------
    if (t < D_MODEL) {
        const float4* wr = (const float4*)(w_down + (size_t)t * BN);
        #pragma unroll
        for (int q = 0; q < 4; ++q) {
            float4 v = wr[q];
            s_wd[(q*4+0)*D_MODEL + t] = v.x;
            s_wd[(q*4+1)*D_MODEL + t] = v.y;
            s_wd[(q*4+2)*D_MODEL + t] = v.z;
            s_wd[(q*4+3)*D_MODEL + t] = v.w;
        }
        s_g [t] = gamma[t];
        s_bt[t] = beta[t];
        s_bu[t] = SCALE * b_up[t];
    }
    {   // w_up (16,768) straight copy, pre-scaled by SCALE
        const float4* src = (const float4*)w_up;
        float4* dst = (float4*)s_wu;
        #pragma unroll
        for (int q = 0; q < 3; ++q) {
            float4 v = src[t + q * TPB];
            v.x *= SCALE; v.y *= SCALE; v.z *= SCALE; v.w *= SCALE;
            dst[t + q * TPB] = v;
        }
    }
    if (t < BN) s_bd[t] = b_down[t];
    __syncthreads();

    // wave k (=w): compute G[k], D[k]; then scale s_wd row k by gamma
    {
        const int k = w;
        float Gp = 0.f, Dp = 0.f;
        #pragma unroll
        for (int q = 0; q < 3; ++q) {
            const int d0 = q * 256 + lane * 4;
            float wv[4], gv[4], bv[4];
            ld4(&s_wd[k * D_MODEL + d0], wv);
            ld4(&s_g [d0], gv);
            ld4(&s_bt[d0], bv);
            #pragma unroll
            for (int c = 0; c < 4; ++c) {
                Gp = fmaf(gv[c], wv[c], Gp);
                Dp = fmaf(bv[c], wv[c], Dp);
                wv[c] *= gv[c];
            }
            *(float4*)&s_wd[k * D_MODEL + d0] = make_float4(wv[0], wv[1], wv[2], wv[3]);
        }
        #pragma unroll
        for (int m = 32; m >= 1; m >>= 1) {
            Gp += __shfl_xor(Gp, m, 64);
            Dp += __shfl_xor(Dp, m, 64);
        }
        if (lane == 0) { s_G[k] = Gp; s_D[k] = Dp; }
    }
    __syncthreads();            // last block-wide barrier

    // block-invariant per-lane constants (k split: A = lane&7, B = 8+(lane&7))
    const int   kA  = lane & 7;
    const float GlA = s_G[kA],          GlB = s_G[8 + kA];
    const float DBA = s_D[kA] + s_bd[kA];
    const float DBB = s_D[8 + kA] + s_bd[8 + kA];
    const float inv_d = 1.0f / (float)D_MODEL;
    const int   dofs = lane * 4;        // chunked d-ownership: d = q*256 + lane*4

    for (int pp = 0; pp < PASSES; ++pp) {
        const int r0 = blockIdx.x * ROWS_PER_BLOCK + pp * (WAVES * RPW) + w * RPW;
        const float* xp = x + (size_t)r0 * D_MODEL;

        // ---- load 2 rows; each instr is contiguous 1KB/wave ----
        float xv[RPW][12];
        #pragma unroll
        for (int j = 0; j < RPW; ++j)
            #pragma unroll
            for (int q = 0; q < 3; ++q)
                ld4(xp + (size_t)j * D_MODEL + q * 256 + dofs, &xv[j][q * 4]);

        // ---- LN stats, independent in-wave butterflies ----
        float s1[RPW], s2[RPW];
        #pragma unroll
        for (int j = 0; j < RPW; ++j) {
            s1[j] = 0.f; s2[j] = 0.f;
            #pragma unroll
            for (int i = 0; i < 12; ++i) {
                s1[j] += xv[j][i];
                s2[j]  = fmaf(xv[j][i], xv[j][i], s2[j]);
            }
        }
        #pragma unroll
        for (int m = 32; m >= 1; m >>= 1) {
            #pragma unroll
            for (int j = 0; j < RPW; ++j) {
                s1[j] += __shfl_xor(s1[j], m, 64);
                s2[j] += __shfl_xor(s2[j], m, 64);
            }
        }
        float mean[RPW], rs[RPW];
        #pragma unroll
        for (int j = 0; j < RPW; ++j) {
            mean[j] = s1[j] * inv_d;
            rs[j]   = rsqrtf(fmaf(s2[j], inv_d, -(mean[j] * mean[j])) + LN_EPS);
        }

        // ---- down-proj on RAW x (LN folded), two 8-k batches ----
        float dnA[RPW], dnB[RPW];
        #pragma unroll
        for (int h = 0; h < 2; ++h) {          // h=0: k 0..7, h=1: k 8..15
            float p[RPW][8];
            #pragma unroll
            for (int j = 0; j < RPW; ++j)
                #pragma unroll
                for (int i = 0; i < 8; ++i) p[j][i] = 0.f;
            #pragma unroll
            for (int kk = 0; kk < 8; ++kk) {
                const int k = h * 8 + kk;
                #pragma unroll
                for (int q = 0; q < 3; ++q) {
                    float wv[4];
                    ld4(&s_wd[k * D_MODEL + q * 256 + dofs], wv);
                    #pragma unroll
                    for (int j = 0; j < RPW; ++j)
                        #pragma unroll
                        for (int c = 0; c < 4; ++c)
                            p[j][kk] = fmaf(xv[j][q * 4 + c], wv[c], p[j][kk]);
                }
            }
            // split-butterfly: 8 elems over 8-lane groups, then fold groups
            #pragma unroll
            for (int m = 4; m >= 1; m >>= 1) {
                const bool up = (lane & m) != 0;
                #pragma unroll
                for (int j = 0; j < RPW; ++j)
                    #pragma unroll
                    for (int i = 0; i < m; ++i) {
                        float s = up ? p[j][i] : p[j][i + m];
                        float r = __shfl_xor(s, m, 64);
                        p[j][i] = (up ? p[j][i + m] : p[j][i]) + r;
                    }
            }
            #pragma unroll
            for (int j = 0; j < RPW; ++j) {
                float v = p[j][0];
                v += __shfl_xor(v, 8, 64);
                v += __shfl_xor(v, 16, 64);
                v += __shfl_xor(v, 32, 64);
                // lane now holds P[k] for k = h*8 + (lane&7), summed over wave
                const float G  = h ? GlB : GlA;
                const float DB = h ? DBB : DBA;
                const float dv = fmaxf(fmaf(rs[j], fmaf(-mean[j], G, v), DB), 0.f);
                if (h) dnB[j] = dv; else dnA[j] = dv;
            }
        }

        // ---- up-proj + residual + store, per 256-d chunk (acc[2][4] live;
        // dn broadcast via v_readlane -> SGPR operand, ~zero VGPR cost) ----
        float* op = out + (size_t)r0 * D_MODEL;
        #pragma unroll
        for (int q = 0; q < 3; ++q) {
            float buv[4];
            ld4(&s_bu[q * 256 + dofs], buv);
            float acc[RPW][4];
            #pragma unroll
            for (int j = 0; j < RPW; ++j)
                #pragma unroll
                for (int c = 0; c < 4; ++c) acc[j][c] = buv[c];

            #pragma unroll
            for (int k = 0; k < BN; ++k) {
                float wv[4];
                ld4(&s_wu[k * D_MODEL + q * 256 + dofs], wv);
                float dbk[RPW];
                #pragma unroll
                for (int j = 0; j < RPW; ++j)
                    dbk[j] = (k < 8) ? bcast(dnA[j], k) : bcast(dnB[j], k - 8);
                #pragma unroll
                for (int j = 0; j < RPW; ++j)
                    #pragma unroll
                    for (int c = 0; c < 4; ++c)
                        acc[j][c] = fmaf(dbk[j], wv[c], acc[j][c]);
            }
            #pragma unroll
            for (int j = 0; j < RPW; ++j) {
                float4 o;
                o.x = xv[j][q*4+0] + acc[j][0];
                o.y = xv[j][q*4+1] + acc[j][1];
                o.z = xv[j][q*4+2] + acc[j][2];
                o.w = xv[j][q*4+3] + acc[j][3];
                *(float4*)(op + (size_t)j * D_MODEL + q * 256 + dofs) = o;
            }
        }
    }
}

extern "C" void kernel_launch(void* const* d_in, const int* in_sizes, int n_in,
                              void* d_out, int out_size, void* d_ws, size_t ws_size,
                              hipStream_t stream) {
    const float* x       = (const float*)d_in[0];
    const float* gamma   = (const float*)d_in[1];
    const float* beta    = (const float*)d_in[2];
    const float* w_down  = (const float*)d_in[3];
    const float* b_down  = (const float*)d_in[4];
    const float* w_up    = (const float*)d_in[5];
    const float* b_up    = (const float*)d_in[6];
    float* out = (float*)d_out;

    adapter_fused<<<NBLOCKS, TPB, 0, stream>>>(x, gamma, beta, w_down, b_down,
                                               w_up, b_up, out);
}